// Round 4
// baseline (5583.672 us; speedup 1.0000x reference)
//
#include <hip/hip_runtime.h>
#include <hip/hip_bf16.h>

// ---------------------------------------------------------------------------
// CustomLSTM: x(64,1024,512), W(512,2048), U(512,2048), bias(2048)
// out = per-step hidden states (64,1024,512). Runtime dtype detection
// (fp32 vs bf16) via bit-pattern vote; all math is fp32-exact via split-bf16
// (hi+lo) MFMA operands; xW kept fp32 (host falls back to bf16 if ws small).
// ---------------------------------------------------------------------------

typedef short bf16x8 __attribute__((ext_vector_type(8)));
typedef float f32x4 __attribute__((ext_vector_type(4)));

#define MFMA16(a, b, c) __builtin_amdgcn_mfma_f32_16x16x32_bf16(a, b, c, 0, 0, 0)

__device__ __forceinline__ float bf2f(__hip_bfloat16 x) { return __bfloat162float(x); }
__device__ __forceinline__ __hip_bfloat16 f2bf(float x) { return __float2bfloat16(x); }

__device__ __forceinline__ void gl2lds16(const void* g, void* l) {
  __builtin_amdgcn_global_load_lds(
      (const __attribute__((address_space(1))) unsigned int*)g,
      (__attribute__((address_space(3))) unsigned int*)l, 16, 0, 0);
}

// ws layout (bytes)
#define OFF_XHI  0ull
#define OFF_XLO  67108864ull
#define OFF_WHI  134217728ull
#define OFF_WLO  136314880ull
#define OFF_UHI  138412032ull
#define OFF_ULO  140509184ull
#define OFF_BIAS 142606336ull
#define OFF_H    142614528ull   // 4 planes x 65536: hhi0,hhi1,hlo0,hlo1
#define OFF_CNT  142876672ull
#define OFF_FLAG 142877184ull
#define OFF_XW   142877696ull
#define XW32_NEED (OFF_XW + 536870912ull)

// --------------------------- dtype sniffer ----------------------------------
// bf16 halves: exponent bits [14:7] land in [0x70,0x84] for N(0,1) data;
// fp32 words have ~uniform mantissa there (~8% hit). 64-sample majority vote.
__global__ __launch_bounds__(64) void kSniff(const unsigned* __restrict__ x,
                                             int* __restrict__ flag) {
  int tid = threadIdx.x;
  unsigned w = x[tid * 97 + 5];
  int e = (w >> 7) & 0xFF;
  int hit = (e >= 0x70 && e <= 0x84) ? 1 : 0;
  unsigned long long m = __ballot(hit);
  if (tid == 0) *flag = (__popcll(m) > 32) ? 1 : 0;   // 1 = bf16, 0 = fp32
}

// --------------------------- x -> hi/lo bf16 planes (8 elems/thread) --------
__global__ __launch_bounds__(256) void kSplitX(const void* __restrict__ src,
                                               __hip_bfloat16* __restrict__ xhi,
                                               __hip_bfloat16* __restrict__ xlo,
                                               const int* __restrict__ flag) {
  const int fl = *flag;
  size_t id = (size_t)blockIdx.x * 256 + threadIdx.x;   // 4,194,304 threads
  float v[8];
  if (fl) {
    bf16x8 a = ((const bf16x8*)src)[id];
#pragma unroll
    for (int i = 0; i < 8; ++i) {
      short s = a[i];
      __hip_bfloat16 b;
      __builtin_memcpy(&b, &s, 2);
      v[i] = bf2f(b);
    }
  } else {
    float4 a = ((const float4*)src)[id * 2], b = ((const float4*)src)[id * 2 + 1];
    v[0] = a.x; v[1] = a.y; v[2] = a.z; v[3] = a.w;
    v[4] = b.x; v[5] = b.y; v[6] = b.z; v[7] = b.w;
  }
  bf16x8 hi8, lo8;
#pragma unroll
  for (int i = 0; i < 8; ++i) {
    __hip_bfloat16 h = f2bf(v[i]);
    __hip_bfloat16 l = f2bf(v[i] - bf2f(h));   // exactly 0 when input was bf16
    short sh, sl;
    __builtin_memcpy(&sh, &h, 2);
    __builtin_memcpy(&sl, &l, 2);
    hi8[i] = sh; lo8[i] = sl;
  }
  ((bf16x8*)xhi)[id] = hi8;
  ((bf16x8*)xlo)[id] = lo8;
}

// ------------------ transpose + split (512x2048 -> 2048x512 planes) ---------
__global__ __launch_bounds__(256) void kSplitT(const void* __restrict__ src,
                                               __hip_bfloat16* __restrict__ dhi,
                                               __hip_bfloat16* __restrict__ dlo,
                                               const int* __restrict__ flag) {
  const int fl = *flag;
  int id = blockIdx.x * 256 + threadIdx.x;              // 1,048,576
  int nrow = id >> 9, k = id & 511;
  float v = fl ? bf2f(((const __hip_bfloat16*)src)[k * 2048 + nrow])
               : ((const float*)src)[k * 2048 + nrow];
  __hip_bfloat16 hi = f2bf(v);
  dhi[id] = hi;
  dlo[id] = f2bf(v - bf2f(hi));
}

// --------------------------- bias -> fp32 -----------------------------------
__global__ __launch_bounds__(256) void kBias(const void* __restrict__ src,
                                             float* __restrict__ dst,
                                             const int* __restrict__ flag) {
  const int fl = *flag;
  int id = blockIdx.x * 256 + threadIdx.x;              // 2048
  dst[id] = fl ? bf2f(((const __hip_bfloat16*)src)[id]) : ((const float*)src)[id];
}

// --------------------------- projection GEMM --------------------------------
// C(65536x2048) = (x_hi+x_lo) @ (W_hi+W_lo) + bias, stored at [t][b][col]
// (row permutation r2 = (m&1023)*64 + (m>>10)). fp32 or bf16 store per xw32.
__global__ __launch_bounds__(256) void kProj(
    const __hip_bfloat16* __restrict__ Xh, const __hip_bfloat16* __restrict__ Xl,
    const __hip_bfloat16* __restrict__ Wh, const __hip_bfloat16* __restrict__ Wl,
    const float* __restrict__ bias_f, const int* __restrict__ flag,
    void* __restrict__ xW, const int xw32) {
  __shared__ __hip_bfloat16 lAh[128 * 32], lBh[128 * 32];
  __shared__ __hip_bfloat16 lAl[128 * 32], lBl[128 * 32];
  const int fl = *flag;                                 // 1 => lo planes all 0

  const int tid = threadIdx.x;
  const int bm = blockIdx.x >> 4, bn = blockIdx.x & 15;
  const int m0 = bm * 128, n0 = bn * 128;
  const int wave = tid >> 6, lane = tid & 63;
  const int quad = lane >> 4, l16 = lane & 15;
  const int wr = (wave >> 1) * 64, wc = (wave & 1) * 64;
  const int rowA = tid >> 2, kbA = tid & 3;

  f32x4 acc[4][4] = {};

#pragma unroll 1
  for (int kt = 0; kt < 16; ++kt) {
    const int k0 = kt * 32;
    gl2lds16(Xh + (size_t)(m0 + rowA) * 512 + k0 + kbA * 8, &lAh[tid * 8]);
    gl2lds16(Xh + (size_t)(m0 + rowA + 64) * 512 + k0 + kbA * 8, &lAh[(tid + 256) * 8]);
    gl2lds16(Wh + (size_t)(n0 + rowA) * 512 + k0 + kbA * 8, &lBh[tid * 8]);
    gl2lds16(Wh + (size_t)(n0 + rowA + 64) * 512 + k0 + kbA * 8, &lBh[(tid + 256) * 8]);
    if (!fl) {
      gl2lds16(Xl + (size_t)(m0 + rowA) * 512 + k0 + kbA * 8, &lAl[tid * 8]);
      gl2lds16(Xl + (size_t)(m0 + rowA + 64) * 512 + k0 + kbA * 8, &lAl[(tid + 256) * 8]);
      gl2lds16(Wl + (size_t)(n0 + rowA) * 512 + k0 + kbA * 8, &lBl[tid * 8]);
      gl2lds16(Wl + (size_t)(n0 + rowA + 64) * 512 + k0 + kbA * 8, &lBl[(tid + 256) * 8]);
    }
    __syncthreads();

    bf16x8 ah[4], bh[4];
#pragma unroll
    for (int i = 0; i < 4; ++i)
      ah[i] = *(const bf16x8*)&lAh[(wr + i * 16 + l16) * 32 + quad * 8];
#pragma unroll
    for (int i = 0; i < 4; ++i)
      bh[i] = *(const bf16x8*)&lBh[(wc + i * 16 + l16) * 32 + quad * 8];
#pragma unroll
    for (int i = 0; i < 4; ++i)
#pragma unroll
      for (int j = 0; j < 4; ++j) acc[i][j] = MFMA16(ah[i], bh[j], acc[i][j]);

    if (!fl) {
      bf16x8 al[4], bl[4];
#pragma unroll
      for (int i = 0; i < 4; ++i)
        al[i] = *(const bf16x8*)&lAl[(wr + i * 16 + l16) * 32 + quad * 8];
#pragma unroll
      for (int i = 0; i < 4; ++i)
        bl[i] = *(const bf16x8*)&lBl[(wc + i * 16 + l16) * 32 + quad * 8];
#pragma unroll
      for (int i = 0; i < 4; ++i)
#pragma unroll
        for (int j = 0; j < 4; ++j) {
          acc[i][j] = MFMA16(al[i], bh[j], acc[i][j]);
          acc[i][j] = MFMA16(ah[i], bl[j], acc[i][j]);
        }
    }
    __syncthreads();
  }

#pragma unroll
  for (int j = 0; j < 4; ++j) {
    const int cg = n0 + wc + j * 16 + l16;
    const float bv = bias_f[cg];
#pragma unroll
    for (int i = 0; i < 4; ++i) {
      const int rg = m0 + wr + i * 16 + quad * 4;       // m = b*1024 + t
#pragma unroll
      for (int r = 0; r < 4; ++r) {
        const int m = rg + r;
        const size_t r2 = (size_t)(m & 1023) * 64 + (m >> 10);  // [t][b]
        const float val = acc[i][j][r] + bv;
        if (xw32) ((float*)xW)[r2 * 2048 + cg] = val;
        else      ((__hip_bfloat16*)xW)[r2 * 2048 + cg] = f2bf(val);
      }
    }
  }
}

// --------------------------- recurrence -------------------------------------
// 256 WGs = 4 batch-clusters x 64 col-WGs. U hi+lo slices LDS-resident.
// gates = h_hi@U_hi + h_lo@U_hi + h_hi@U_lo + xW ; h exchanged as hi+lo bf16
// planes via agent-scope relaxed atomics; per-cluster counter barrier.
__global__ __launch_bounds__(256) void kLSTM(
    const void* __restrict__ xW, const int xw32,
    const __hip_bfloat16* __restrict__ Uhi, const __hip_bfloat16* __restrict__ Ulo,
    __hip_bfloat16* __restrict__ hbase,
    unsigned* __restrict__ counters,
    const int* __restrict__ flag,
    void* __restrict__ out) {
  __shared__ __hip_bfloat16 Ulh[32 * 520];
  __shared__ __hip_bfloat16 Ull[32 * 520];
  __shared__ float red[4 * 16 * 32];
  __shared__ float gsum[16 * 33];

  const int fl = *flag;
  const int tid = threadIdx.x;
  const int bg = blockIdx.x >> 6, cg = blockIdx.x & 63;
  const int b0 = bg * 16, j0 = cg * 8;
  const int wave = tid >> 6, lane = tid & 63;
  const int quad = lane >> 4, l16 = lane & 15;
  unsigned* cnt = counters + bg * 32;

  __hip_bfloat16* hhi[2] = {hbase, hbase + 32768};
  __hip_bfloat16* hlo[2] = {hbase + 65536, hbase + 98304};

  // preload U slices: row n_local = gt*8+jl  <->  U col gt*512 + j0 + jl
#pragma unroll
  for (int i = 0; i < 8; ++i) {
    int c = tid + i * 256;
    int row = c >> 6, kb = c & 63;
    int gg = (row >> 3) * 512 + j0 + (row & 7);
    *(bf16x8*)&Ulh[row * 520 + kb * 8] = *(const bf16x8*)(Uhi + (size_t)gg * 512 + kb * 8);
    *(bf16x8*)&Ull[row * 520 + kb * 8] = *(const bf16x8*)(Ulo + (size_t)gg * 512 + kb * 8);
  }
  __syncthreads();

  float c_state = 0.f;
  const int bl_e = tid >> 5, nl_e = tid & 31;
  const int gg1 = (nl_e >> 3) * 512 + j0 + (nl_e & 7);
  const int b_act = tid >> 3, j_act = tid & 7;

#pragma unroll 1
  for (int t = 0; t < 1024; ++t) {
    const __hip_bfloat16* phi = hhi[t & 1];
    const __hip_bfloat16* plo = hlo[t & 1];
    __hip_bfloat16* nhi = hhi[(t & 1) ^ 1];
    __hip_bfloat16* nlo = hlo[(t & 1) ^ 1];

    // (A) xW prefetch ([t][b][col] layout -> contiguous slab per step)
    const size_t xi1 = ((size_t)t * 64 + b0 + bl_e) * 2048 + gg1;
    const size_t xi2 = ((size_t)t * 64 + b0 + bl_e + 8) * 2048 + gg1;
    float xw1, xw2;
    if (xw32) { xw1 = ((const float*)xW)[xi1]; xw2 = ((const float*)xW)[xi2]; }
    else { xw1 = bf2f(((const __hip_bfloat16*)xW)[xi1]); xw2 = bf2f(((const __hip_bfloat16*)xW)[xi2]); }

    // (B) load h fragments (hi+lo) via agent-scope atomic u64 (IC-coherent)
    const size_t hoff = (size_t)(b0 + l16) * 512 + wave * 128 + quad * 8;
    bf16x8 ah[4], al[4];
#pragma unroll
    for (int ks = 0; ks < 4; ++ks) {
      union { unsigned long long q[2]; bf16x8 v; } uh, ul;
      const unsigned long long* ph = (const unsigned long long*)(phi + hoff + ks * 32);
      const unsigned long long* pl = (const unsigned long long*)(plo + hoff + ks * 32);
      uh.q[0] = __hip_atomic_load(ph, __ATOMIC_RELAXED, __HIP_MEMORY_SCOPE_AGENT);
      uh.q[1] = __hip_atomic_load(ph + 1, __ATOMIC_RELAXED, __HIP_MEMORY_SCOPE_AGENT);
      ul.q[0] = __hip_atomic_load(pl, __ATOMIC_RELAXED, __HIP_MEMORY_SCOPE_AGENT);
      ul.q[1] = __hip_atomic_load(pl + 1, __ATOMIC_RELAXED, __HIP_MEMORY_SCOPE_AGENT);
      ah[ks] = uh.v; al[ks] = ul.v;
    }

    // (C) 24 MFMAs: hi@Uhi + lo@Uhi + hi@Ulo, K split over 4 waves
    f32x4 acc0 = {}, acc1 = {};
#pragma unroll
    for (int ks = 0; ks < 4; ++ks) {
      const int k = wave * 128 + ks * 32 + quad * 8;
      bf16x8 b0h = *(const bf16x8*)&Ulh[l16 * 520 + k];
      bf16x8 b1h = *(const bf16x8*)&Ulh[(16 + l16) * 520 + k];
      bf16x8 b0l = *(const bf16x8*)&Ull[l16 * 520 + k];
      bf16x8 b1l = *(const bf16x8*)&Ull[(16 + l16) * 520 + k];
      acc0 = MFMA16(ah[ks], b0h, acc0);
      acc0 = MFMA16(al[ks], b0h, acc0);
      acc0 = MFMA16(ah[ks], b0l, acc0);
      acc1 = MFMA16(ah[ks], b1h, acc1);
      acc1 = MFMA16(al[ks], b1h, acc1);
      acc1 = MFMA16(ah[ks], b1l, acc1);
    }

    // (D) K-partials to LDS: D[row=quad*4+r][col=l16]
#pragma unroll
    for (int r = 0; r < 4; ++r) {
      red[(wave * 16 + quad * 4 + r) * 32 + l16] = acc0[r];
      red[(wave * 16 + quad * 4 + r) * 32 + 16 + l16] = acc1[r];
    }
    __syncthreads();

    // (E) reduce over waves + xW
    {
      float s1 = xw1, s2 = xw2;
#pragma unroll
      for (int w = 0; w < 4; ++w) {
        s1 += red[(w * 16 + bl_e) * 32 + nl_e];
        s2 += red[(w * 16 + bl_e + 8) * 32 + nl_e];
      }
      gsum[bl_e * 33 + nl_e] = s1;
      gsum[(bl_e + 8) * 33 + nl_e] = s2;
    }
    __syncthreads();

    // (F) activations + state update (16 batch x 8 hidden)
    if (tid < 128) {
      float xg_i = gsum[b_act * 33 + j_act];
      float xg_f = gsum[b_act * 33 + 8 + j_act];
      float xg_g = gsum[b_act * 33 + 16 + j_act];
      float xg_o = gsum[b_act * 33 + 24 + j_act];
      float ig = 1.f / (1.f + __expf(-xg_i));
      float fg = 1.f / (1.f + __expf(-xg_f));
      float gv = 1.f - 2.f / (__expf(2.f * xg_g) + 1.f);
      float og = 1.f / (1.f + __expf(-xg_o));
      c_state = fg * c_state + ig * gv;
      float th = 1.f - 2.f / (__expf(2.f * c_state) + 1.f);
      float h = og * th;

      __hip_bfloat16 hb_hi = f2bf(h);
      __hip_bfloat16 hb_lo = f2bf(h - bf2f(hb_hi));
      unsigned short us_h, us_l;
      __builtin_memcpy(&us_h, &hb_hi, 2);
      __builtin_memcpy(&us_l, &hb_lo, 2);
      unsigned oh = (unsigned)(unsigned short)__shfl_xor((int)us_h, 1);
      unsigned ol = (unsigned)(unsigned short)__shfl_xor((int)us_l, 1);
      if (!(j_act & 1)) {
        const size_t hp = (size_t)(b0 + b_act) * 512 + j0 + j_act;
        __hip_atomic_store((unsigned*)(nhi + hp), ((unsigned)us_h) | (oh << 16),
                           __ATOMIC_RELAXED, __HIP_MEMORY_SCOPE_AGENT);
        __hip_atomic_store((unsigned*)(nlo + hp), ((unsigned)us_l) | (ol << 16),
                           __ATOMIC_RELAXED, __HIP_MEMORY_SCOPE_AGENT);
      }
      const size_t oidx = ((size_t)(b0 + b_act) * 1024 + t) * 512 + j0 + j_act;
      if (fl) ((__hip_bfloat16*)out)[oidx] = hb_hi;
      else    ((float*)out)[oidx] = h;
    }

    // (G) cluster barrier (64 WGs)
    __syncthreads();
    if (tid == 0) {
      __hip_atomic_fetch_add(cnt, 1u, __ATOMIC_RELAXED, __HIP_MEMORY_SCOPE_AGENT);
      const unsigned target = 64u * (unsigned)(t + 1);
      while (__hip_atomic_load(cnt, __ATOMIC_RELAXED, __HIP_MEMORY_SCOPE_AGENT) < target)
        __builtin_amdgcn_s_sleep(1);
    }
    __syncthreads();
  }
}

// --------------------------- launch -----------------------------------------
extern "C" void kernel_launch(void* const* d_in, const int* in_sizes, int n_in,
                              void* d_out, int out_size, void* d_ws, size_t ws_size,
                              hipStream_t stream) {
  (void)in_sizes; (void)n_in; (void)out_size;
  const void* x    = d_in[0];
  const void* W    = d_in[1];
  const void* U    = d_in[2];
  const void* bias = d_in[3];

  char* ws = (char*)d_ws;
  __hip_bfloat16* xhi  = (__hip_bfloat16*)(ws + OFF_XHI);
  __hip_bfloat16* xlo  = (__hip_bfloat16*)(ws + OFF_XLO);
  __hip_bfloat16* Whi  = (__hip_bfloat16*)(ws + OFF_WHI);
  __hip_bfloat16* Wlo  = (__hip_bfloat16*)(ws + OFF_WLO);
  __hip_bfloat16* Uhi  = (__hip_bfloat16*)(ws + OFF_UHI);
  __hip_bfloat16* Ulo  = (__hip_bfloat16*)(ws + OFF_ULO);
  float* bias_f        = (float*)(ws + OFF_BIAS);
  __hip_bfloat16* hbase = (__hip_bfloat16*)(ws + OFF_H);
  unsigned* counters   = (unsigned*)(ws + OFF_CNT);
  int* flag            = (int*)(ws + OFF_FLAG);
  void* xW             = (void*)(ws + OFF_XW);

  const int xw32 = (ws_size >= XW32_NEED) ? 1 : 0;   // fp32 xW if ws permits

  // zero h planes + counters (ws re-poisoned 0xAA before every launch)
  (void)hipMemsetAsync(ws + OFF_H, 0, 262144 + 512 + 64, stream);

  kSniff<<<1, 64, 0, stream>>>((const unsigned*)x, flag);
  kSplitX<<<16384, 256, 0, stream>>>(x, xhi, xlo, flag);
  kSplitT<<<4096, 256, 0, stream>>>(W, Whi, Wlo, flag);
  kSplitT<<<4096, 256, 0, stream>>>(U, Uhi, Ulo, flag);
  kBias<<<8, 256, 0, stream>>>(bias, bias_f, flag);
  kProj<<<8192, 256, 0, stream>>>(xhi, xlo, Whi, Wlo, bias_f, flag, xW, xw32);
  kLSTM<<<256, 256, 0, stream>>>(xW, xw32, Uhi, Ulo, hbase, counters, flag, d_out);
}